// Round 3
// baseline (513.693 us; speedup 1.0000x reference)
//
#include <hip/hip_runtime.h>

#define EMBED 100
#define MATSZ (EMBED * EMBED)      // 10000 floats per functor matrix
#define NVEC4 (MATSZ / 4)          // 2500 float4 per matrix
#define BLOCK 256
#define ITERS 10                   // ceil(NVEC4 / BLOCK)
#define FUNC_VOCAB 10000
#define K_CAP 8                    // pairs per functor handled in the fused pass
#define LEFT_BLOCKS 16

// ---- workspace layout (ints) ----
// [0, FUNC_VOCAB)                      counts
// [FUNC_VOCAB]                         leftover_count
// [10016, 10016 + FUNC_VOCAB*K_CAP)    buckets
// [10016 + FUNC_VOCAB*K_CAP, +8192)    leftover list
#define WS_COUNTS   0
#define WS_LC       FUNC_VOCAB
#define WS_BUCKET   10016
#define WS_LEFT     (10016 + FUNC_VOCAB * K_CAP)

__global__ __launch_bounds__(BLOCK) void zero_ws_kernel(int* __restrict__ w) {
    int t = blockIdx.x * BLOCK + threadIdx.x;
    if (t <= FUNC_VOCAB) w[t] = 0;   // counts + leftover_count
}

__global__ __launch_bounds__(BLOCK) void scatter_kernel(
    const int* __restrict__ Xf, int* __restrict__ ws, int B)
{
    int t = blockIdx.x * BLOCK + threadIdx.x;
    if (t >= B) return;
    int f = Xf[t];
    int slot = atomicAdd(&ws[WS_COUNTS + f], 1);
    if (slot < K_CAP) {
        ws[WS_BUCKET + f * K_CAP + slot] = t;
    } else {
        int s = atomicAdd(&ws[WS_LC], 1);
        ws[WS_LEFT + s] = t;
    }
}

// One block per functor: read M once (registers), evaluate all (<=K_CAP) pairs.
__global__ __launch_bounds__(BLOCK) void pass2_kernel(
    const int* __restrict__ Xa,
    const int* __restrict__ Xc,
    const float* __restrict__ noun_matrix,
    const float* __restrict__ functor_table,
    const float* __restrict__ context_table,
    float* __restrict__ out,
    const int* __restrict__ ws)
{
    const int f   = blockIdx.x;
    const int tid = threadIdx.x;

    int c = ws[WS_COUNTS + f];
    if (c <= 0) return;
    if (c > K_CAP) c = K_CAP;

    __shared__ float4 s_arg4[K_CAP][EMBED / 4];
    __shared__ float  s_ctx [K_CAP][EMBED];
    __shared__ float  s_part[BLOCK / 64];
    __shared__ int    s_b   [K_CAP];

    // Issue all matrix loads first (overlaps with vector staging below).
    const float4* __restrict__ M4 =
        (const float4*)(functor_table + (size_t)f * MATSZ);
    float4 mv[ITERS];
    #pragma unroll
    for (int k = 0; k < ITERS; ++k) {
        int v  = tid + k * BLOCK;
        int vc = v < NVEC4 ? v : (NVEC4 - 1);
        mv[k] = M4[vc];
    }

    // Stage arg/ctx for all pairs: 32-thread group per pair.
    const int p = tid >> 5;      // 0..7
    const int r = tid & 31;      // 0..31
    if (p < c) {
        int b = ws[WS_BUCKET + f * K_CAP + p];
        if (r == 0) s_b[p] = b;
        if (r < EMBED / 4) {
            s_arg4[p][r] = ((const float4*)(noun_matrix  + (size_t)Xa[b] * EMBED))[r];
            ((float4*)s_ctx[p])[r] = ((const float4*)(context_table + (size_t)Xc[b] * EMBED))[r];
        }
    }
    __syncthreads();

    for (int p2 = 0; p2 < c; ++p2) {
        float acc = 0.0f;
        #pragma unroll
        for (int k = 0; k < ITERS; ++k) {
            int v  = tid + k * BLOCK;
            int vc = v < NVEC4 ? v : (NVEC4 - 1);
            int fi = vc * 4;
            int i  = fi / EMBED;
            int j  = fi - i * EMBED;
            float4 a = s_arg4[p2][j >> 2];
            float4 m = mv[k];
            float d4 = m.x * a.x + m.y * a.y + m.z * a.z + m.w * a.w;
            float cc = (v < NVEC4) ? s_ctx[p2][i] : 0.0f;
            acc = fmaf(cc, d4, acc);
        }
        #pragma unroll
        for (int off = 32; off > 0; off >>= 1)
            acc += __shfl_down(acc, off, 64);
        if ((tid & 63) == 0) s_part[tid >> 6] = acc;
        __syncthreads();
        if (tid == 0)
            out[s_b[p2]] = s_part[0] + s_part[1] + s_part[2] + s_part[3];
        __syncthreads();
    }
}

// Overflow path (count > K_CAP): one block per leftover element, direct reads.
__global__ __launch_bounds__(BLOCK) void leftover_kernel(
    const int* __restrict__ Xa,
    const int* __restrict__ Xf,
    const int* __restrict__ Xc,
    const float* __restrict__ noun_matrix,
    const float* __restrict__ functor_table,
    const float* __restrict__ context_table,
    float* __restrict__ out,
    const int* __restrict__ ws)
{
    const int tid = threadIdx.x;
    const int n   = ws[WS_LC];

    __shared__ float4 s_arg4[EMBED / 4];
    __shared__ float  s_ctx[EMBED];
    __shared__ float  s_part[BLOCK / 64];

    for (int idx = blockIdx.x; idx < n; idx += LEFT_BLOCKS) {
        int b = ws[WS_LEFT + idx];
        if (tid < EMBED / 4) {
            s_arg4[tid] = ((const float4*)(noun_matrix + (size_t)Xa[b] * EMBED))[tid];
            ((float4*)s_ctx)[tid] = ((const float4*)(context_table + (size_t)Xc[b] * EMBED))[tid];
        }
        __syncthreads();

        const float4* __restrict__ M4 =
            (const float4*)(functor_table + (size_t)Xf[b] * MATSZ);
        float acc = 0.0f;
        #pragma unroll
        for (int k = 0; k < ITERS; ++k) {
            int v  = tid + k * BLOCK;
            int vc = v < NVEC4 ? v : (NVEC4 - 1);
            int fi = vc * 4;
            int i  = fi / EMBED;
            int j  = fi - i * EMBED;
            float4 a = s_arg4[j >> 2];
            float4 m = M4[vc];
            float d4 = m.x * a.x + m.y * a.y + m.z * a.z + m.w * a.w;
            float cc = (v < NVEC4) ? s_ctx[i] : 0.0f;
            acc = fmaf(cc, d4, acc);
        }
        #pragma unroll
        for (int off = 32; off > 0; off >>= 1)
            acc += __shfl_down(acc, off, 64);
        if ((tid & 63) == 0) s_part[tid >> 6] = acc;
        __syncthreads();
        if (tid == 0)
            out[b] = s_part[0] + s_part[1] + s_part[2] + s_part[3];
        __syncthreads();
    }
}

extern "C" void kernel_launch(void* const* d_in, const int* in_sizes, int n_in,
                              void* d_out, int out_size, void* d_ws, size_t ws_size,
                              hipStream_t stream) {
    const int*   Xa   = (const int*)d_in[0];
    const int*   Xf   = (const int*)d_in[1];
    const int*   Xc   = (const int*)d_in[2];
    const float* noun = (const float*)d_in[3];
    const float* func = (const float*)d_in[4];
    const float* ctxt = (const float*)d_in[5];
    float*       out  = (float*)d_out;
    int*         ws   = (int*)d_ws;

    const int B = in_sizes[0];   // 8192

    zero_ws_kernel<<<(FUNC_VOCAB + BLOCK) / BLOCK, BLOCK, 0, stream>>>(ws);
    scatter_kernel<<<(B + BLOCK - 1) / BLOCK, BLOCK, 0, stream>>>(Xf, ws, B);
    pass2_kernel<<<FUNC_VOCAB, BLOCK, 0, stream>>>(Xa, Xc, noun, func, ctxt, out, ws);
    leftover_kernel<<<LEFT_BLOCKS, BLOCK, 0, stream>>>(Xa, Xf, Xc, noun, func, ctxt, out, ws);
}

// Round 4
// 509.775 us; speedup vs baseline: 1.0077x; 1.0077x over previous
//
#include <hip/hip_runtime.h>

#define EMBED 100
#define MATSZ (EMBED * EMBED)   // 10000 floats per functor matrix
#define NVEC4 (MATSZ / 4)       // 2500 float4 per matrix
#define BLOCK 256
#define ITERS 10                // ceil(NVEC4 / BLOCK) — compile-time constant

// One block per batch element: out[b] = ctx^T · M · arg.
// Measured R1-R3: kernel is gather-BW-bound on unique functor bytes (~224 MB,
// L3 absorbs duplicates); dur_us is dominated by a fixed ~450 µs harness
// restore/poison floor. This is the simplest variant at the measured floor.
__global__ __launch_bounds__(BLOCK) void msg_kernel(
    const int* __restrict__ Xa,
    const int* __restrict__ Xf,
    const int* __restrict__ Xc,
    const float* __restrict__ noun_matrix,    // [50000, 100]
    const float* __restrict__ functor_table,  // [10000, 10000]
    const float* __restrict__ context_table,  // [50000, 100]
    float* __restrict__ out)                  // [B]
{
    const int b   = blockIdx.x;
    const int tid = threadIdx.x;

    __shared__ float4 s_arg4[EMBED / 4];   // arg vector as 25 float4
    __shared__ float  s_ctx[EMBED];
    __shared__ float  s_part[BLOCK / 64];

    const int ia  = Xa[b];
    const int ifn = Xf[b];
    const int ic  = Xc[b];

    // Stage vectors. Rows are 400 B (16B-aligned), so float4 loads are legal.
    if (tid < EMBED / 4) {
        s_arg4[tid] = ((const float4*)(noun_matrix + (size_t)ia * EMBED))[tid];
    }
    if (tid < EMBED) {
        s_ctx[tid] = context_table[(size_t)ic * EMBED + tid];
    }
    __syncthreads();

    const float4* __restrict__ M4 =
        (const float4*)(functor_table + (size_t)ifn * MATSZ);

    // Constant trip count; all 10 global_load_dwordx4 in flight before use.
    float4 mv[ITERS];
    #pragma unroll
    for (int k = 0; k < ITERS; ++k) {
        int v  = tid + k * BLOCK;
        int vc = v < NVEC4 ? v : (NVEC4 - 1);   // clamped: always in-bounds
        mv[k] = M4[vc];
    }

    float acc = 0.0f;
    #pragma unroll
    for (int k = 0; k < ITERS; ++k) {
        int v  = tid + k * BLOCK;
        int vc = v < NVEC4 ? v : (NVEC4 - 1);
        int f  = vc * 4;
        int i  = f / EMBED;          // row (ctx index)
        int j  = f - i * EMBED;      // col (arg index), multiple of 4
        float4 a = s_arg4[j >> 2];   // single ds_read_b128
        float4 m = mv[k];
        float dot4 = m.x * a.x + m.y * a.y + m.z * a.z + m.w * a.w;
        float c = (v < NVEC4) ? s_ctx[i] : 0.0f;
        acc = fmaf(c, dot4, acc);
    }

    // Wave64 shuffle reduction, then cross-wave via LDS.
    #pragma unroll
    for (int off = 32; off > 0; off >>= 1)
        acc += __shfl_down(acc, off, 64);

    const int wave = tid >> 6;
    const int lane = tid & 63;
    if (lane == 0) s_part[wave] = acc;
    __syncthreads();

    if (tid == 0) {
        float r = 0.0f;
        #pragma unroll
        for (int w = 0; w < BLOCK / 64; ++w) r += s_part[w];
        out[b] = r;
    }
}

extern "C" void kernel_launch(void* const* d_in, const int* in_sizes, int n_in,
                              void* d_out, int out_size, void* d_ws, size_t ws_size,
                              hipStream_t stream) {
    const int*   Xa   = (const int*)d_in[0];
    const int*   Xf   = (const int*)d_in[1];
    const int*   Xc   = (const int*)d_in[2];
    const float* noun = (const float*)d_in[3];
    const float* func = (const float*)d_in[4];
    const float* ctxt = (const float*)d_in[5];
    float*       out  = (float*)d_out;

    const int B = in_sizes[0];   // 8192
    msg_kernel<<<B, BLOCK, 0, stream>>>(Xa, Xf, Xc, noun, func, ctxt, out);
}